// Round 1
// baseline (394.920 us; speedup 1.0000x reference)
//
#include <hip/hip_runtime.h>
#include <hip/hip_bf16.h>

#define NN 100000
#define EE 1600000
#define ET (EE + NN)          // edges incl. self loops
#define HID 64
#define NEG 0.2f

// ---------------- kernel 0: h1 = x@W1, ss1 = h1.a_src1, sd1 = h1.a_dst1 ----------------
__global__ __launch_bounds__(256) void k_proj(const float* __restrict__ x,
                                              const float* __restrict__ W1,
                                              const float* __restrict__ a_src1,
                                              const float* __restrict__ a_dst1,
                                              float* __restrict__ h1,
                                              float* __restrict__ ss1,
                                              float* __restrict__ sd1) {
    int wid  = threadIdx.x >> 6;
    int lane = threadIdx.x & 63;
    int n = blockIdx.x * 4 + wid;
    if (n >= NN) return;
    float h = 0.f;
#pragma unroll
    for (int k = 0; k < 5; ++k) h += x[n * 5 + k] * W1[k * HID + lane];
    h1[(size_t)n * HID + lane] = h;
    float a = h * a_src1[lane];
    float b = h * a_dst1[lane];
#pragma unroll
    for (int o = 32; o; o >>= 1) { a += __shfl_xor(a, o); b += __shfl_xor(b, o); }
    if (lane == 0) { ss1[n] = a; sd1[n] = b; }
}

// ---------------- CSR build ----------------
__global__ __launch_bounds__(256) void k_count(const int* __restrict__ ei, int* __restrict__ cnt) {
    int i = blockIdx.x * 256 + threadIdx.x;
    if (i >= ET) return;
    int d = (i < EE) ? ei[EE + i] : (i - EE);
    atomicAdd(&cnt[d], 1);
}

__global__ __launch_bounds__(256) void k_scan1(const int* __restrict__ cnt,
                                               int* __restrict__ rowptr,
                                               int* __restrict__ bsum) {
    __shared__ int tmp[256];
    int i = blockIdx.x * 256 + threadIdx.x;
    int v = (i < NN) ? cnt[i] : 0;
    tmp[threadIdx.x] = v;
    __syncthreads();
    for (int o = 1; o < 256; o <<= 1) {
        int t = (threadIdx.x >= o) ? tmp[threadIdx.x - o] : 0;
        __syncthreads();
        tmp[threadIdx.x] += t;
        __syncthreads();
    }
    if (i < NN) rowptr[i] = tmp[threadIdx.x] - v;   // exclusive
    if (threadIdx.x == 255) bsum[blockIdx.x] = tmp[255];
}

__global__ __launch_bounds__(512) void k_scan2(int* __restrict__ bsum, int nb) {
    __shared__ int tmp[512];
    int v = (threadIdx.x < nb) ? bsum[threadIdx.x] : 0;
    tmp[threadIdx.x] = v;
    __syncthreads();
    for (int o = 1; o < 512; o <<= 1) {
        int t = (threadIdx.x >= o) ? tmp[threadIdx.x - o] : 0;
        __syncthreads();
        tmp[threadIdx.x] += t;
        __syncthreads();
    }
    if (threadIdx.x < nb) bsum[threadIdx.x] = tmp[threadIdx.x] - v;  // exclusive
}

__global__ __launch_bounds__(256) void k_scan3(int* __restrict__ rowptr, const int* __restrict__ bsum) {
    int i = blockIdx.x * 256 + threadIdx.x;
    if (i < NN) rowptr[i] += bsum[blockIdx.x];
}

__global__ __launch_bounds__(256) void k_scatter(const int* __restrict__ ei,
                                                 int* __restrict__ fill,
                                                 int* __restrict__ adj) {
    int i = blockIdx.x * 256 + threadIdx.x;
    if (i >= ET) return;
    int s, d;
    if (i < EE) { s = ei[i]; d = ei[EE + i]; }
    else        { s = i - EE; d = i - EE; }
    int pos = atomicAdd(&fill[d], 1);
    adj[pos] = s;
}

// ---------------- layer 1 softmax-aggregate (+ fused bias/ReLU/W2/a2) ----------------
__global__ __launch_bounds__(256) void k_agg1(const int* __restrict__ rowptr,
                                              const int* __restrict__ cnt,
                                              const int* __restrict__ adj,
                                              const float* __restrict__ ss1,
                                              const float* __restrict__ sd1,
                                              const float* __restrict__ h1,
                                              const float* __restrict__ b1,
                                              const float* __restrict__ W2,
                                              const float* __restrict__ as2,
                                              const float* __restrict__ ad2,
                                              float* __restrict__ h2,
                                              float* __restrict__ ss2,
                                              float* __restrict__ sd2) {
    int wid  = threadIdx.x >> 6;
    int lane = threadIdx.x & 63;
    int n = blockIdx.x * 4 + wid;
    if (n >= NN) return;
    int off = rowptr[n], deg = cnt[n];
    float sdn = sd1[n];

    // pass 1: segment max
    float m = -1e30f;
    for (int j0 = 0; j0 < deg; j0 += 64) {
        int j = j0 + lane;
        if (j < deg) {
            int s = adj[off + j];
            float e = ss1[s] + sdn;
            e = e > 0.f ? e : NEG * e;
            m = fmaxf(m, e);
        }
    }
#pragma unroll
    for (int o = 32; o; o >>= 1) m = fmaxf(m, __shfl_xor(m, o));

    // pass 2: denom
    float dsum = 0.f;
    for (int j0 = 0; j0 < deg; j0 += 64) {
        int j = j0 + lane;
        if (j < deg) {
            int s = adj[off + j];
            float e = ss1[s] + sdn;
            e = e > 0.f ? e : NEG * e;
            dsum += __expf(e - m);
        }
    }
#pragma unroll
    for (int o = 32; o; o >>= 1) dsum += __shfl_xor(dsum, o);
    float inv = 1.0f / dsum;

    // pass 3: weighted feature aggregation (lane = feature)
    float acc = 0.f;
    for (int j0 = 0; j0 < deg; j0 += 64) {
        int j = j0 + lane;
        float w = 0.f; int s = 0;
        if (j < deg) {
            s = adj[off + j];
            float e = ss1[s] + sdn;
            e = e > 0.f ? e : NEG * e;
            w = __expf(e - m) * inv;
        }
        int lim = deg - j0; if (lim > 64) lim = 64;
        for (int t = 0; t < lim; ++t) {
            float c = __shfl(w, t);
            int  sj = __shfl(s, t);
            acc += c * h1[(size_t)sj * HID + lane];
        }
    }

    // epilogue: +b1, ReLU, fused layer-2 projection h2 = relu(out1) @ W2
    float v = acc + b1[lane];
    v = fmaxf(v, 0.f);
    float p = v * W2[lane];
#pragma unroll
    for (int o = 32; o; o >>= 1) p += __shfl_xor(p, o);
    if (lane == 0) {
        h2[n]  = p;
        ss2[n] = p * as2[0];
        sd2[n] = p * ad2[0];
    }
}

// ---------------- layer 2 softmax-aggregate (scalar features) ----------------
__global__ __launch_bounds__(256) void k_agg2(const int* __restrict__ rowptr,
                                              const int* __restrict__ cnt,
                                              const int* __restrict__ adj,
                                              const float* __restrict__ ss2,
                                              const float* __restrict__ sd2,
                                              const float* __restrict__ h2,
                                              const float* __restrict__ b2,
                                              float* __restrict__ out) {
    int wid  = threadIdx.x >> 6;
    int lane = threadIdx.x & 63;
    int n = blockIdx.x * 4 + wid;
    if (n >= NN) return;
    int off = rowptr[n], deg = cnt[n];
    float sdn = sd2[n];

    float m = -1e30f;
    for (int j0 = 0; j0 < deg; j0 += 64) {
        int j = j0 + lane;
        if (j < deg) {
            int s = adj[off + j];
            float e = ss2[s] + sdn;
            e = e > 0.f ? e : NEG * e;
            m = fmaxf(m, e);
        }
    }
#pragma unroll
    for (int o = 32; o; o >>= 1) m = fmaxf(m, __shfl_xor(m, o));

    float dsum = 0.f, nsum = 0.f;
    for (int j0 = 0; j0 < deg; j0 += 64) {
        int j = j0 + lane;
        if (j < deg) {
            int s = adj[off + j];
            float e = ss2[s] + sdn;
            e = e > 0.f ? e : NEG * e;
            float ex = __expf(e - m);
            dsum += ex;
            nsum += ex * h2[s];
        }
    }
#pragma unroll
    for (int o = 32; o; o >>= 1) { dsum += __shfl_xor(dsum, o); nsum += __shfl_xor(nsum, o); }

    if (lane == 0) out[n] = nsum / dsum + b2[0];
}

extern "C" void kernel_launch(void* const* d_in, const int* in_sizes, int n_in,
                              void* d_out, int out_size, void* d_ws, size_t ws_size,
                              hipStream_t stream) {
    const float* x      = (const float*)d_in[0];
    const int*   ei     = (const int*)d_in[1];      // [2, E] int32
    const float* W1     = (const float*)d_in[2];
    const float* a_src1 = (const float*)d_in[3];
    const float* a_dst1 = (const float*)d_in[4];
    const float* b1     = (const float*)d_in[5];
    const float* W2     = (const float*)d_in[6];
    const float* as2    = (const float*)d_in[7];
    const float* ad2    = (const float*)d_in[8];
    const float* b2     = (const float*)d_in[9];
    float* out = (float*)d_out;

    // workspace layout (all 4-byte elements)
    float* h1  = (float*)d_ws;                 // N*64
    float* ss1 = h1 + (size_t)NN * HID;        // N
    float* sd1 = ss1 + NN;                     // N
    float* h2  = sd1 + NN;                     // N
    float* ss2 = h2 + NN;                      // N
    float* sd2 = ss2 + NN;                     // N
    int* cnt    = (int*)(sd2 + NN);            // N
    int* rowptr = cnt + NN;                    // N
    int* fill   = rowptr + NN;                 // N
    int* bsum   = fill + NN;                   // 512
    int* adj    = bsum + 512;                  // ET

    const int NB = (NN + 255) / 256;           // 391 scan blocks

    hipMemsetAsync(cnt, 0, NN * sizeof(int), stream);

    k_proj<<<(NN + 3) / 4, 256, 0, stream>>>(x, W1, a_src1, a_dst1, h1, ss1, sd1);
    k_count<<<(ET + 255) / 256, 256, 0, stream>>>(ei, cnt);
    k_scan1<<<NB, 256, 0, stream>>>(cnt, rowptr, bsum);
    k_scan2<<<1, 512, 0, stream>>>(bsum, NB);
    k_scan3<<<NB, 256, 0, stream>>>(rowptr, bsum);
    hipMemcpyAsync(fill, rowptr, NN * sizeof(int), hipMemcpyDeviceToDevice, stream);
    k_scatter<<<(ET + 255) / 256, 256, 0, stream>>>(ei, fill, adj);
    k_agg1<<<(NN + 3) / 4, 256, 0, stream>>>(rowptr, cnt, adj, ss1, sd1, h1,
                                             b1, W2, as2, ad2, h2, ss2, sd2);
    k_agg2<<<(NN + 3) / 4, 256, 0, stream>>>(rowptr, cnt, adj, ss2, sd2, h2, b2, out);
}

// Round 2
// 176.672 us; speedup vs baseline: 2.2353x; 2.2353x over previous
//
#include <hip/hip_runtime.h>
#include <hip/hip_bf16.h>

#define NN 100000
#define EE 1600000
#define ET (EE + NN)            // edges incl. self loops
#define HID 64
#define NEG 0.2f
#define NBUK 782                // ceil(NN/128) buckets of 128 dst nodes
#define SCT_TILE 4096           // edges per block in count/scatter phases
#define SH_CAP 4096             // per-bucket LDS capacity (mean 2176, sigma~47)

// ---------------- kernel 0: h1 = x@W1, ss1 = h1.a_src1, sd1 = h1.a_dst1 ----------------
__global__ __launch_bounds__(256) void k_proj(const float* __restrict__ x,
                                              const float* __restrict__ W1,
                                              const float* __restrict__ a_src1,
                                              const float* __restrict__ a_dst1,
                                              float* __restrict__ h1,
                                              float* __restrict__ ss1,
                                              float* __restrict__ sd1) {
    int wid  = threadIdx.x >> 6;
    int lane = threadIdx.x & 63;
    int n = blockIdx.x * 4 + wid;
    if (n >= NN) return;
    float h = 0.f;
#pragma unroll
    for (int k = 0; k < 5; ++k) h += x[n * 5 + k] * W1[k * HID + lane];
    h1[(size_t)n * HID + lane] = h;
    float a = h * a_src1[lane];
    float b = h * a_dst1[lane];
#pragma unroll
    for (int o = 32; o; o >>= 1) { a += __shfl_xor(a, o); b += __shfl_xor(b, o); }
    if (lane == 0) { ss1[n] = a; sd1[n] = b; }
}

// ---------------- CSR build: bucketed counting sort ----------------
// Phase A: per-bucket edge counts (LDS histogram per block)
__global__ __launch_bounds__(256) void k_bcount(const int* __restrict__ ei,
                                                int* __restrict__ bcnt) {
    __shared__ int h[NBUK];
    for (int i = threadIdx.x; i < NBUK; i += 256) h[i] = 0;
    __syncthreads();
    int base = blockIdx.x * SCT_TILE;
#pragma unroll
    for (int it = 0; it < SCT_TILE / 256; ++it) {
        int i = base + it * 256 + threadIdx.x;
        if (i < ET) {
            int d = (i < EE) ? ei[EE + i] : (i - EE);
            atomicAdd(&h[d >> 7], 1);
        }
    }
    __syncthreads();
    for (int i = threadIdx.x; i < NBUK; i += 256)
        if (h[i]) atomicAdd(&bcnt[i], h[i]);
}

// Phase B: exclusive scan of bucket counts (one block)
__global__ __launch_bounds__(1024) void k_bscan(const int* __restrict__ bcnt,
                                                int* __restrict__ bbase,
                                                int* __restrict__ bcur) {
    __shared__ int t0[1024];
    int tid = threadIdx.x;
    int v = (tid < NBUK) ? bcnt[tid] : 0;
    t0[tid] = v;
    __syncthreads();
    for (int o = 1; o < 1024; o <<= 1) {
        int t = (tid >= o) ? t0[tid - o] : 0;
        __syncthreads();
        t0[tid] += t;
        __syncthreads();
    }
    if (tid < NBUK) { int ex = t0[tid] - v; bbase[tid] = ex; bcur[tid] = ex; }
}

// Phase C: scatter packed (local_dst<<17 | src) into bucket regions,
// block-level LDS pre-aggregation for contiguous allocation per bucket.
__global__ __launch_bounds__(256) void k_bscatter(const int* __restrict__ ei,
                                                  int* __restrict__ bcur,
                                                  unsigned* __restrict__ pairs) {
    __shared__ int h[NBUK];
    __shared__ int cur[NBUK];
    for (int i = threadIdx.x; i < NBUK; i += 256) h[i] = 0;
    __syncthreads();
    unsigned pk[SCT_TILE / 256];
    int bb[SCT_TILE / 256];
    int base = blockIdx.x * SCT_TILE;
#pragma unroll
    for (int it = 0; it < SCT_TILE / 256; ++it) {
        int i = base + it * 256 + threadIdx.x;
        if (i < ET) {
            int s, d;
            if (i < EE) { s = ei[i]; d = ei[EE + i]; }
            else        { s = i - EE; d = s; }
            int b = d >> 7;
            pk[it] = ((unsigned)(d & 127) << 17) | (unsigned)s;
            bb[it] = b;
            atomicAdd(&h[b], 1);
        } else bb[it] = -1;
    }
    __syncthreads();
    for (int i = threadIdx.x; i < NBUK; i += 256) {
        int c = h[i];
        cur[i] = c ? atomicAdd(&bcur[i], c) : 0;
    }
    __syncthreads();
#pragma unroll
    for (int it = 0; it < SCT_TILE / 256; ++it) {
        if (bb[it] >= 0) {
            int pos = atomicAdd(&cur[bb[it]], 1);
            pairs[pos] = pk[it];
        }
    }
}

// Phase D: per-bucket counting sort (in LDS), emit adj + rowptr + cnt.
// pairs and adj alias the same memory: all reads happen before the barrier.
__global__ __launch_bounds__(256) void k_bsort(const int* __restrict__ bcnt,
                                               const int* __restrict__ bbase,
                                               unsigned* __restrict__ pairs,
                                               int* __restrict__ rowptr,
                                               int* __restrict__ cntd) {
    __shared__ unsigned sp[SH_CAP];
    __shared__ int hist[128], sc[128], cur2[128];
    int b = blockIdx.x;
    int cnt = bcnt[b];
    if (cnt > SH_CAP) cnt = SH_CAP;   // statistically impossible; memory-safety only
    int base = bbase[b];
    int tid = threadIdx.x;
    if (tid < 128) hist[tid] = 0;
    __syncthreads();
    for (int i = tid; i < cnt; i += 256) {
        unsigned p = pairs[base + i];
        sp[i] = p;
        atomicAdd(&hist[p >> 17], 1);
    }
    __syncthreads();
    if (tid < 128) sc[tid] = hist[tid];
    __syncthreads();
    for (int o = 1; o < 128; o <<= 1) {
        int t = (tid < 128 && tid >= o) ? sc[tid - o] : 0;
        __syncthreads();
        if (tid < 128) sc[tid] += t;
        __syncthreads();
    }
    int nbase = b << 7;
    if (tid < 128 && nbase + tid < NN) {
        int ex = sc[tid] - hist[tid];
        rowptr[nbase + tid] = base + ex;
        cntd[nbase + tid]   = hist[tid];
        cur2[tid] = ex;
    }
    __syncthreads();
    int* adj = (int*)pairs;
    for (int i = tid; i < cnt; i += 256) {
        unsigned p = sp[i];
        int ld = p >> 17;
        int pos = atomicAdd(&cur2[ld], 1);
        adj[base + pos] = (int)(p & 0x1FFFF);
    }
}

// ---------------- layer 1 softmax-aggregate (+ fused bias/ReLU/W2) ----------------
__global__ __launch_bounds__(256) void k_agg1(const int* __restrict__ rowptr,
                                              const int* __restrict__ cntd,
                                              const int* __restrict__ adj,
                                              const float* __restrict__ ss1,
                                              const float* __restrict__ sd1,
                                              const float* __restrict__ h1,
                                              const float* __restrict__ b1,
                                              const float* __restrict__ W2,
                                              float* __restrict__ h2) {
    __shared__ float lw[4][64];
    __shared__ int   lsrc[4][64];
    int wid  = threadIdx.x >> 6;
    int lane = threadIdx.x & 63;
    int n = blockIdx.x * 4 + wid;
    if (n >= NN) return;
    int off = rowptr[n], deg = cntd[n];
    float sdn = sd1[n];
    float acc = 0.f;

    if (deg <= 64) {
        // ---- fast path: logits live in registers, one ss1 gather total ----
        int s = 0; float e = -1e30f;
        if (lane < deg) {
            s = adj[off + lane];
            float t = ss1[s] + sdn;
            e = t > 0.f ? t : NEG * t;
        }
        float m = e;
#pragma unroll
        for (int o = 32; o; o >>= 1) m = fmaxf(m, __shfl_xor(m, o));
        float p = (lane < deg) ? __expf(e - m) : 0.f;
        float ds = p;
#pragma unroll
        for (int o = 32; o; o >>= 1) ds += __shfl_xor(ds, o);
        float w = p * (1.0f / ds);
        lw[wid][lane] = w;
        lsrc[wid][lane] = s;
        // wave-private LDS: no barrier needed
        int t = 0;
        for (; t + 4 <= deg; t += 4) {
            float c0 = lw[wid][t],   c1 = lw[wid][t+1];
            float c2 = lw[wid][t+2], c3 = lw[wid][t+3];
            int s0 = lsrc[wid][t],   s1 = lsrc[wid][t+1];
            int s2 = lsrc[wid][t+2], s3 = lsrc[wid][t+3];
            float v0 = h1[(size_t)s0 * HID + lane];
            float v1 = h1[(size_t)s1 * HID + lane];
            float v2 = h1[(size_t)s2 * HID + lane];
            float v3 = h1[(size_t)s3 * HID + lane];
            acc += c0 * v0 + c1 * v1 + c2 * v2 + c3 * v3;
        }
        for (; t < deg; ++t)
            acc += lw[wid][t] * h1[(size_t)lsrc[wid][t] * HID + lane];
    } else {
        // ---- generic chunked 3-pass path (rare) ----
        float m = -1e30f;
        for (int j0 = 0; j0 < deg; j0 += 64) {
            int j = j0 + lane;
            if (j < deg) {
                int s = adj[off + j];
                float e = ss1[s] + sdn;
                e = e > 0.f ? e : NEG * e;
                m = fmaxf(m, e);
            }
        }
#pragma unroll
        for (int o = 32; o; o >>= 1) m = fmaxf(m, __shfl_xor(m, o));
        float dsum = 0.f;
        for (int j0 = 0; j0 < deg; j0 += 64) {
            int j = j0 + lane;
            if (j < deg) {
                int s = adj[off + j];
                float e = ss1[s] + sdn;
                e = e > 0.f ? e : NEG * e;
                dsum += __expf(e - m);
            }
        }
#pragma unroll
        for (int o = 32; o; o >>= 1) dsum += __shfl_xor(dsum, o);
        float inv = 1.0f / dsum;
        for (int j0 = 0; j0 < deg; j0 += 64) {
            int j = j0 + lane;
            float w = 0.f; int s = 0;
            if (j < deg) {
                s = adj[off + j];
                float e = ss1[s] + sdn;
                e = e > 0.f ? e : NEG * e;
                w = __expf(e - m) * inv;
            }
            int lim = deg - j0; if (lim > 64) lim = 64;
            for (int t = 0; t < lim; ++t) {
                float c = __shfl(w, t);
                int  sj = __shfl(s, t);
                acc += c * h1[(size_t)sj * HID + lane];
            }
        }
    }

    // epilogue: +b1, ReLU, fused layer-2 projection h2 = relu(out1) @ W2
    float v = acc + b1[lane];
    v = fmaxf(v, 0.f);
    float p2 = v * W2[lane];
#pragma unroll
    for (int o = 32; o; o >>= 1) p2 += __shfl_xor(p2, o);
    if (lane == 0) h2[n] = p2;
}

// ---------------- layer 2 softmax-aggregate (scalar features, single pass) ----------------
__global__ __launch_bounds__(256) void k_agg2(const int* __restrict__ rowptr,
                                              const int* __restrict__ cntd,
                                              const int* __restrict__ adj,
                                              const float* __restrict__ h2,
                                              const float* __restrict__ as2,
                                              const float* __restrict__ ad2,
                                              const float* __restrict__ b2,
                                              float* __restrict__ out) {
    int wid  = threadIdx.x >> 6;
    int lane = threadIdx.x & 63;
    int n = blockIdx.x * 4 + wid;
    if (n >= NN) return;
    int off = rowptr[n], deg = cntd[n];
    float as2v = as2[0];
    float sdn = h2[n] * ad2[0];

    if (deg <= 64) {
        float hv = 0.f, e = -1e30f;
        if (lane < deg) {
            int s = adj[off + lane];
            hv = h2[s];
            float t = hv * as2v + sdn;
            e = t > 0.f ? t : NEG * t;
        }
        float m = e;
#pragma unroll
        for (int o = 32; o; o >>= 1) m = fmaxf(m, __shfl_xor(m, o));
        float p = (lane < deg) ? __expf(e - m) : 0.f;
        float ds = p, ns = p * hv;
#pragma unroll
        for (int o = 32; o; o >>= 1) { ds += __shfl_xor(ds, o); ns += __shfl_xor(ns, o); }
        if (lane == 0) out[n] = ns / ds + b2[0];
    } else {
        float m = -1e30f;
        for (int j0 = 0; j0 < deg; j0 += 64) {
            int j = j0 + lane;
            if (j < deg) {
                int s = adj[off + j];
                float e = h2[s] * as2v + sdn;
                e = e > 0.f ? e : NEG * e;
                m = fmaxf(m, e);
            }
        }
#pragma unroll
        for (int o = 32; o; o >>= 1) m = fmaxf(m, __shfl_xor(m, o));
        float dsum = 0.f, nsum = 0.f;
        for (int j0 = 0; j0 < deg; j0 += 64) {
            int j = j0 + lane;
            if (j < deg) {
                int s = adj[off + j];
                float hv = h2[s];
                float e = hv * as2v + sdn;
                e = e > 0.f ? e : NEG * e;
                float ex = __expf(e - m);
                dsum += ex;
                nsum += ex * hv;
            }
        }
#pragma unroll
        for (int o = 32; o; o >>= 1) { dsum += __shfl_xor(dsum, o); nsum += __shfl_xor(nsum, o); }
        if (lane == 0) out[n] = nsum / dsum + b2[0];
    }
}

extern "C" void kernel_launch(void* const* d_in, const int* in_sizes, int n_in,
                              void* d_out, int out_size, void* d_ws, size_t ws_size,
                              hipStream_t stream) {
    const float* x      = (const float*)d_in[0];
    const int*   ei     = (const int*)d_in[1];
    const float* W1     = (const float*)d_in[2];
    const float* a_src1 = (const float*)d_in[3];
    const float* a_dst1 = (const float*)d_in[4];
    const float* b1     = (const float*)d_in[5];
    const float* W2     = (const float*)d_in[6];
    const float* as2    = (const float*)d_in[7];
    const float* ad2    = (const float*)d_in[8];
    const float* b2     = (const float*)d_in[9];
    float* out = (float*)d_out;

    // workspace layout (all 4-byte elements)
    float* h1   = (float*)d_ws;                // N*64
    float* ss1  = h1 + (size_t)NN * HID;       // N
    float* sd1  = ss1 + NN;                    // N
    float* h2   = sd1 + NN;                    // N
    int* rowptr = (int*)(h2 + NN);             // N
    int* cntd   = rowptr + NN;                 // N
    int* bcnt   = cntd + NN;                   // 1024
    int* bbase  = bcnt + 1024;                 // 1024
    int* bcur   = bbase + 1024;                // 1024
    unsigned* pairs = (unsigned*)(bcur + 1024);// ET (reused as adj)
    int* adj    = (int*)pairs;

    const int NSCT = (ET + SCT_TILE - 1) / SCT_TILE;   // 416

    hipMemsetAsync(bcnt, 0, 1024 * sizeof(int), stream);

    k_proj<<<(NN + 3) / 4, 256, 0, stream>>>(x, W1, a_src1, a_dst1, h1, ss1, sd1);
    k_bcount<<<NSCT, 256, 0, stream>>>(ei, bcnt);
    k_bscan<<<1, 1024, 0, stream>>>(bcnt, bbase, bcur);
    k_bscatter<<<NSCT, 256, 0, stream>>>(ei, bcur, pairs);
    k_bsort<<<NBUK, 256, 0, stream>>>(bcnt, bbase, pairs, rowptr, cntd);
    k_agg1<<<(NN + 3) / 4, 256, 0, stream>>>(rowptr, cntd, adj, ss1, sd1, h1, b1, W2, h2);
    k_agg2<<<(NN + 3) / 4, 256, 0, stream>>>(rowptr, cntd, adj, h2, as2, ad2, b2, out);
}